// Round 9
// baseline (476.233 us; speedup 1.0000x reference)
//
#include <hip/hip_runtime.h>
#include <hip/hip_bf16.h>

// Few-shot matching-network head + Conv4 backbone (MI355X, gfx950). Round 9.
//
// R8: 461 us. conv2@400: MfmaUtil 8.8 / VALU 5.3 / HBM 26% -> latency-bound,
// and total traffic ~805 MB at ~2.1 TB/s is the wall. This round:
//  - fsc_conv1f_k: im2col FUSED into conv1 GEMM (B-frag gathered in registers,
//    same index math as r7's proven im2col) -> kills B1's 184 MB round-trip.
//  - fsc_convm64_k: 64 cols/wave for conv2/3 (16 MFMA : 8 loads per k-step,
//    2x loads in flight) -> latency hiding + arithmetic intensity.
//  - chunking over concatenated [support;target] image index: 2 chunks of 400.

#define BB 8
#define SS 25
#define TT 75
#define CC 5
#define DD 2304
#define NSUP 200
#define NTGT 600
#define NTOT 800
#define EPSF 1e-8f

typedef __attribute__((ext_vector_type(8))) short bf16x8;
typedef __attribute__((ext_vector_type(4))) float f32x4;

__device__ __forceinline__ float load_ext(const void* p, size_t idx, int isf32) {
  if (isf32) return ((const float*)p)[idx];
  unsigned short u = ((const unsigned short*)p)[idx];
  union { unsigned int i; float f; } v;
  v.i = ((unsigned int)u) << 16;
  return v.f;
}

// ---- dtype probe (proven r3-r8): flag=1 => external data is fp32 ----
__global__ void fsc_probe_dtype_k(const unsigned short* __restrict__ w2raw,
                                  int nelems, int* __restrict__ flag) {
  __shared__ int cnt;
  if (threadIdx.x == 0) cnt = 0;
  __syncthreads();
  int local = 0;
  for (int i = threadIdx.x; i < nelems; i += 256) {
    unsigned short u = w2raw[i];
    int ex = (u >> 7) & 0xFF;
    if (ex != 0 && (ex < 0x69 || ex > 0x84)) local++;
  }
  atomicAdd(&cnt, local);
  __syncthreads();
  if (threadIdx.x == 0) *flag = (cnt > nelems / 8) ? 1 : 0;
}

// ---- conv1 weight repack -> A-frag layout [t=4][lane=64][j=8] bf16 ----
__global__ void fsc_repack_w1f_k(const void* __restrict__ W,
                                 __hip_bfloat16* __restrict__ Wf,
                                 const int* __restrict__ flag) {
  const int isf32 = *flag;
  int i = blockIdx.x * blockDim.x + threadIdx.x;
  if (i >= 2048) return;
  int j = i & 7;
  int lane = (i >> 3) & 63;
  int t = i >> 9;
  int k = (lane >> 4) * 8 + j;
  int co = t * 16 + (lane & 15);
  float v = (k < 27) ? load_ext(W, (size_t)co * 27 + k, isf32) : 0.f;
  Wf[i] = __float2bfloat16(v);
}

// ---- conv2/3/4 weight repack: OIHW [64][64][3][3] -> bf16 A-frag order ----
__global__ void fsc_repack_wm_k(const void* __restrict__ W,
                                __hip_bfloat16* __restrict__ Wf,
                                const int* __restrict__ flag) {
  const int isf32 = *flag;
  int o = blockIdx.x * blockDim.x + threadIdx.x;
  if (o >= 36864) return;
  int j = o & 7;
  int lane = (o >> 3) & 63;
  int t = (o >> 9) & 3;
  int kk = o >> 11;       // 0..17
  int s = kk & 1;
  int khw = kk >> 1;      // kh*3+kw
  int kh = khw / 3, kw = khw - kh * 3;
  int co = t * 16 + (lane & 15);
  int ci = s * 32 + (lane >> 4) * 8 + j;
  float v = load_ext(W, (size_t)((co * 64 + ci) * 3 + kh) * 3 + kw, isf32);
  Wf[o] = __float2bfloat16(v);
}

// ---- zero the 1-px border of an NHWC-padded [N][P][P][64] bf16 buffer ----
template <int P>
__global__ void fsc_zero_border_k(__hip_bfloat16* __restrict__ buf, int N) {
  int i = blockIdx.x * blockDim.x + threadIdx.x;
  const int RP = 4 * P - 4;
  if (i >= N * RP * 64) return;
  int c = i & 63;
  int r = (i >> 6) % RP;
  int n = (i >> 6) / RP;
  int row, colp;
  if (r < P) { row = 0; colp = r; }
  else if (r < 2 * P) { row = P - 1; colp = r - P; }
  else if (r < 3 * P - 2) { row = r - 2 * P + 1; colp = 0; }
  else { row = r - (3 * P - 2) + 1; colp = P - 1; }
  buf[(((size_t)n * P + row) * P + colp) * 64 + c] = __float2bfloat16(0.f);
}

// ---- conv1 fused im2col+GEMM: x [img][3][84][84] -> bf16 NHWC 44-pad.
//      B-frag gathered in registers (index math = r7's proven im2col):
//      k = quad*8+j -> ci=k/9, kh=(k%9)/3, kw=k%3; hi=2ho+kh, wi=2wo+kw. ----
__global__ void fsc_conv1f_k(const void* __restrict__ x, int srcImg0,
                             const __hip_bfloat16* __restrict__ Wf,
                             const void* __restrict__ bias,
                             __hip_bfloat16* __restrict__ out, int dstImg0,
                             int n, const int* __restrict__ flag) {
  const int isf32 = *flag;
  const int wid = blockIdx.x * 4 + (threadIdx.x >> 6);
  const int imgL = wid / 56;
  if (imgL >= n) return;
  const int tl = wid - imgL * 56;
  const int lane = threadIdx.x & 63;
  const int nidx = lane & 15, quad = lane >> 4;

  const int col0 = tl * 32 + nidx;
  const int col1 = col0 + 16;
  const bool val0 = col0 < 1764;
  const bool val1 = col1 < 1764;
  const int ho0 = val0 ? col0 / 42 : 0, wo0 = val0 ? col0 - ho0 * 42 : 0;
  const int ho1 = val1 ? col1 / 42 : 0, wo1 = val1 ? col1 - ho1 * 42 : 0;

  const size_t base = (size_t)(srcImg0 + imgL) * 21168;
  union { unsigned short u[8]; bf16x8 v; } B0, B1;
#pragma unroll
  for (int j = 0; j < 8; ++j) {
    const int k = quad * 8 + j;
    float v0 = 0.f, v1 = 0.f;
    if (k < 27) {
      const int ci = k / 9;
      const int r = k - ci * 9;
      const int kh = r / 3, kw = r - kh * 3;
      {
        const int hi = 2 * ho0 + kh, wi = 2 * wo0 + kw;
        if (val0 && hi < 84 && wi < 84)
          v0 = load_ext(x, base + (ci * 84 + hi) * 84 + wi, isf32);
      }
      {
        const int hi = 2 * ho1 + kh, wi = 2 * wo1 + kw;
        if (val1 && hi < 84 && wi < 84)
          v1 = load_ext(x, base + (ci * 84 + hi) * 84 + wi, isf32);
      }
    }
    B0.u[j] = __bfloat16_as_ushort(__float2bfloat16(v0));
    B1.u[j] = __bfloat16_as_ushort(__float2bfloat16(v1));
  }

  f32x4 acc[2][4];
#pragma unroll
  for (int p = 0; p < 2; ++p)
#pragma unroll
    for (int t = 0; t < 4; ++t) acc[p][t] = (f32x4){0.f, 0.f, 0.f, 0.f};
#pragma unroll
  for (int t = 0; t < 4; ++t) {
    bf16x8 a = *(const bf16x8*)(const void*)(Wf + ((size_t)t * 64 + lane) * 8);
    acc[0][t] = __builtin_amdgcn_mfma_f32_16x16x32_bf16(a, B0.v, acc[0][t], 0, 0, 0);
    acc[1][t] = __builtin_amdgcn_mfma_f32_16x16x32_bf16(a, B1.v, acc[1][t], 0, 0, 0);
  }

  const int img = dstImg0 + imgL;
#pragma unroll
  for (int p = 0; p < 2; ++p) {
    const bool valid = p == 0 ? val0 : val1;
    const int ho = p == 0 ? ho0 : ho1;
    const int wo = p == 0 ? wo0 : wo1;
#pragma unroll
    for (int t = 0; t < 4; ++t) {
      float v[4];
#pragma unroll
      for (int r = 0; r < 4; ++r) {
        const int cout = t * 16 + quad * 4 + r;
        float xv = acc[p][t][r] + load_ext(bias, cout, isf32);
        v[r] = xv > 0.f ? xv : 0.f;
      }
      if (valid) {
        __hip_bfloat16* o = out + (((size_t)img * 44 + (ho + 1)) * 44 + (wo + 1)) * 64 +
                            t * 16 + quad * 4;
        union { unsigned short u[4]; uint2 w; } pk;
#pragma unroll
        for (int r = 0; r < 4; ++r) pk.u[r] = __bfloat16_as_ushort(__float2bfloat16(v[r]));
        *(uint2*)(void*)o = pk.w;
      }
    }
  }
}

// ---- 64-col implicit-GEMM MFMA conv (conv2/conv3): 16 MFMA : 8 loads/k-step ----
template <int HO, int PWI, int PWO, int ROFF>
__global__ void fsc_convm64_k(const __hip_bfloat16* __restrict__ in,
                              const __hip_bfloat16* __restrict__ Wf,
                              const void* __restrict__ bias,
                              __hip_bfloat16* __restrict__ out, int N,
                              const int* __restrict__ flag) {
  constexpr int TPI = (HO * HO + 63) / 64;
  const int wid = blockIdx.x * 4 + (threadIdx.x >> 6);
  const int img = wid / TPI;
  if (img >= N) return;
  const int tl = wid - img * TPI;
  const int lane = threadIdx.x & 63;
  const int nidx = lane & 15, quad = lane >> 4;

  int col[4];
  bool val[4];
  int hoA[4], woA[4];
  const __hip_bfloat16* bsrc[4];
#pragma unroll
  for (int p = 0; p < 4; ++p) {
    col[p] = tl * 64 + p * 16 + nidx;
    val[p] = col[p] < HO * HO;
    if (!val[p]) col[p] = HO * HO - 1;
    hoA[p] = col[p] / HO;
    woA[p] = col[p] - hoA[p] * HO;
    bsrc[p] = in + (((size_t)img * PWI + (2 * hoA[p] + ROFF)) * PWI +
                    (2 * woA[p] + ROFF)) * 64 + quad * 8;
  }
  const __hip_bfloat16* asrc = Wf + lane * 8;

  f32x4 acc[4][4];
#pragma unroll
  for (int p = 0; p < 4; ++p)
#pragma unroll
    for (int t = 0; t < 4; ++t) acc[p][t] = (f32x4){0.f, 0.f, 0.f, 0.f};

#pragma unroll
  for (int kk = 0; kk < 18; ++kk) {
    const int s = kk & 1;
    const int khw = kk >> 1;
    const int kh = khw / 3, kw = khw - kh * 3;
    const int boff = (kh * PWI + kw) * 64 + s * 32;
    bf16x8 b[4];
#pragma unroll
    for (int p = 0; p < 4; ++p) b[p] = *(const bf16x8*)(const void*)(bsrc[p] + boff);
#pragma unroll
    for (int t = 0; t < 4; ++t) {
      bf16x8 a = *(const bf16x8*)(const void*)(asrc + (kk * 4 + t) * 512);
#pragma unroll
      for (int p = 0; p < 4; ++p)
        acc[p][t] = __builtin_amdgcn_mfma_f32_16x16x32_bf16(a, b[p], acc[p][t], 0, 0, 0);
    }
  }

  const int isf32 = *flag;
#pragma unroll
  for (int p = 0; p < 4; ++p) {
#pragma unroll
    for (int t = 0; t < 4; ++t) {
      float v[4];
#pragma unroll
      for (int r = 0; r < 4; ++r) {
        const int cout = t * 16 + quad * 4 + r;
        float xv = acc[p][t][r] + load_ext(bias, cout, isf32);
        v[r] = xv > 0.f ? xv : 0.f;
      }
      if (val[p]) {
        __hip_bfloat16* o = out + (((size_t)img * PWO + (hoA[p] + 1)) * PWO +
                                   (woA[p] + 1)) * 64 + t * 16 + quad * 4;
        union { unsigned short u[4]; uint2 w; } pk;
#pragma unroll
        for (int r = 0; r < 4; ++r) pk.u[r] = __bfloat16_as_ushort(__float2bfloat16(v[r]));
        *(uint2*)(void*)o = pk.w;
      }
    }
  }
}

// ---- 32-col MFMA conv, EMB output (conv4; proven r6-r8) ----
__global__ void fsc_conv4_k(const __hip_bfloat16* __restrict__ in,
                            const __hip_bfloat16* __restrict__ Wf,
                            const void* __restrict__ bias, float* __restrict__ emb,
                            int N, const int* __restrict__ flag) {
  constexpr int HO = 6, PWI = 13;
  constexpr int TPI = 2;  // ceil(36/32)
  const int wid = blockIdx.x * 4 + (threadIdx.x >> 6);
  const int img = wid / TPI;
  if (img >= N) return;
  const int tl = wid - img * TPI;
  const int lane = threadIdx.x & 63;
  const int nidx = lane & 15, quad = lane >> 4;

  int col0 = tl * 32 + nidx;
  int col1 = col0 + 16;
  const bool val0 = col0 < HO * HO;
  const bool val1 = col1 < HO * HO;
  if (!val0) col0 = HO * HO - 1;
  if (!val1) col1 = HO * HO - 1;
  const int ho0 = col0 / HO, wo0 = col0 - ho0 * HO;
  const int ho1 = col1 / HO, wo1 = col1 - ho1 * HO;

  const __hip_bfloat16* bsrc0 =
      in + (((size_t)img * PWI + 2 * ho0) * PWI + 2 * wo0) * 64 + quad * 8;
  const __hip_bfloat16* bsrc1 =
      in + (((size_t)img * PWI + 2 * ho1) * PWI + 2 * wo1) * 64 + quad * 8;
  const __hip_bfloat16* asrc = Wf + lane * 8;

  f32x4 acc[2][4];
#pragma unroll
  for (int p = 0; p < 2; ++p)
#pragma unroll
    for (int t = 0; t < 4; ++t) acc[p][t] = (f32x4){0.f, 0.f, 0.f, 0.f};

#pragma unroll
  for (int kk = 0; kk < 18; ++kk) {
    const int s = kk & 1;
    const int khw = kk >> 1;
    const int kh = khw / 3, kw = khw - kh * 3;
    const int boff = (kh * PWI + kw) * 64 + s * 32;
    bf16x8 b0 = *(const bf16x8*)(const void*)(bsrc0 + boff);
    bf16x8 b1 = *(const bf16x8*)(const void*)(bsrc1 + boff);
#pragma unroll
    for (int t = 0; t < 4; ++t) {
      bf16x8 a = *(const bf16x8*)(const void*)(asrc + (kk * 4 + t) * 512);
      acc[0][t] = __builtin_amdgcn_mfma_f32_16x16x32_bf16(a, b0, acc[0][t], 0, 0, 0);
      acc[1][t] = __builtin_amdgcn_mfma_f32_16x16x32_bf16(a, b1, acc[1][t], 0, 0, 0);
    }
  }

  const int isf32 = *flag;
#pragma unroll
  for (int p = 0; p < 2; ++p) {
    const bool valid = p == 0 ? val0 : val1;
    const int col = p == 0 ? col0 : col1;
#pragma unroll
    for (int t = 0; t < 4; ++t) {
      float v[4];
#pragma unroll
      for (int r = 0; r < 4; ++r) {
        const int cout = t * 16 + quad * 4 + r;
        float xv = acc[p][t][r] + load_ext(bias, cout, isf32);
        v[r] = xv > 0.f ? xv : 0.f;
      }
      if (valid) {
        float* o = emb + ((size_t)img * 36 + col) * 64 + t * 16 + quad * 4;
        *(f32x4*)(void*)o = (f32x4){v[0], v[1], v[2], v[3]};
      }
    }
  }
}

// ---- head (proven r3-r8) ----
__global__ void fsc_proto_k(const float* __restrict__ emb_s, const int* __restrict__ y,
                            float* __restrict__ protos) {
  int i = blockIdx.x * blockDim.x + threadIdx.x;
  if (i >= BB * CC * DD) return;
  int d = i % DD;
  int bc = i / DD;
  int c = bc % CC;
  int b = bc / CC;
  float sum = 0.f;
  for (int s = 0; s < SS; ++s) {
    if (y[b * SS + s] % CC == c) sum += emb_s[(size_t)(b * SS + s) * DD + d];
  }
  protos[i] = sum * 0.2f;
}

__global__ void fsc_pnorm_k(const float* __restrict__ protos, float* __restrict__ pn) {
  __shared__ float red[4];
  __shared__ float inv;
  const int bc = blockIdx.x;
  const float* p = protos + (size_t)bc * DD;
  float ss = 0.f;
  for (int d = threadIdx.x; d < DD; d += 256) { float v = p[d]; ss += v * v; }
#pragma unroll
  for (int off = 32; off > 0; off >>= 1) ss += __shfl_down(ss, off);
  if ((threadIdx.x & 63) == 0) red[threadIdx.x >> 6] = ss;
  __syncthreads();
  if (threadIdx.x == 0) {
    float nrm = sqrtf(red[0] + red[1] + red[2] + red[3]);
    nrm = nrm > EPSF ? nrm : EPSF;
    inv = 1.f / nrm;
  }
  __syncthreads();
  float sc = inv;
  for (int d = threadIdx.x; d < DD; d += 256) pn[(size_t)bc * DD + d] = p[d] * sc;
}

__global__ void fsc_preds_k(const float* __restrict__ emb_t, const float* __restrict__ pn,
                            void* __restrict__ out, const int* __restrict__ flag) {
  __shared__ float red[4][6];
  __shared__ float fin[6];
  const int isf32 = *flag;
  const int bt = blockIdx.x;
  const int b = bt / TT;
  const float* et = emb_t + (size_t)bt * DD;
  float e[9];
#pragma unroll
  for (int k = 0; k < 9; ++k) e[k] = et[threadIdx.x + 256 * k];
  float vals[6];
  {
    float ss = 0.f;
#pragma unroll
    for (int k = 0; k < 9; ++k) ss += e[k] * e[k];
    vals[0] = ss;
  }
  const float* pb = pn + (size_t)b * CC * DD;
#pragma unroll
  for (int c = 0; c < CC; ++c) {
    float s = 0.f;
#pragma unroll
    for (int k = 0; k < 9; ++k) s += e[k] * pb[(size_t)c * DD + threadIdx.x + 256 * k];
    vals[1 + c] = s;
  }
#pragma unroll
  for (int v = 0; v < 6; ++v) {
#pragma unroll
    for (int off = 32; off > 0; off >>= 1) vals[v] += __shfl_down(vals[v], off);
  }
  if ((threadIdx.x & 63) == 0) {
#pragma unroll
    for (int v = 0; v < 6; ++v) red[threadIdx.x >> 6][v] = vals[v];
  }
  __syncthreads();
  if (threadIdx.x < 6)
    fin[threadIdx.x] = red[0][threadIdx.x] + red[1][threadIdx.x] +
                       red[2][threadIdx.x] + red[3][threadIdx.x];
  __syncthreads();
  if (threadIdx.x < CC) {
    float nt = sqrtf(fin[0]);
    nt = nt > EPSF ? nt : EPSF;
    float r = fin[1 + threadIdx.x] / nt;
    if (isf32) ((float*)out)[(size_t)bt * CC + threadIdx.x] = r;
    else ((__hip_bfloat16*)out)[(size_t)bt * CC + threadIdx.x] = __float2bfloat16(r);
  }
}

static inline int fsc_cdiv(int a, int b) { return (a + b - 1) / b; }
static inline int imin(int a, int b) { return a < b ? a : b; }
static inline int imax(int a, int b) { return a > b ? a : b; }

extern "C" void kernel_launch(void* const* d_in, const int* in_sizes, int n_in,
                              void* d_out, int out_size, void* d_ws, size_t ws_size,
                              hipStream_t stream) {
  const void* xs = d_in[0];
  const void* xt = d_in[1];
  const int* y = (const int*)d_in[2];
  const void* W1 = d_in[3];
  const void* b1 = d_in[4];
  const void* W2 = d_in[5];
  const void* b2 = d_in[6];
  const void* W3 = d_in[7];
  const void* b3 = d_in[8];
  const void* W4 = d_in[9];
  const void* b4 = d_in[10];

  // ---- workspace layout: fixed ~25.6 MB + A1/A2 chunk buffers ----
  char* w = (char*)d_ws;
  int* flag = (int*)w;                      w += 256;
  __hip_bfloat16* Wf1 = (__hip_bfloat16*)w; w += 2048 * 2;
  __hip_bfloat16* Wf2 = (__hip_bfloat16*)w; w += 36864 * 2;
  __hip_bfloat16* Wf3 = (__hip_bfloat16*)w; w += 36864 * 2;
  __hip_bfloat16* Wf4 = (__hip_bfloat16*)w; w += 36864 * 2;
  float* protos = (float*)w;                w += (size_t)BB * CC * DD * 4;
  float* pn = (float*)w;                    w += (size_t)BB * CC * DD * 4;
  float* emb = (float*)w;                   w += (size_t)NTOT * DD * 4;           // 7.37 MB
  __hip_bfloat16* C3 = (__hip_bfloat16*)w;  w += (size_t)NTOT * 13 * 13 * 64 * 2; // 17.3 MB
  char* chunk0 = w;
  const size_t fixedB = (size_t)(w - (char*)d_ws);
  const size_t szA1 = (size_t)44 * 44 * 64 * 2;   // 247,808 B/img
  const size_t szA2 = (size_t)23 * 23 * 64 * 2;   //  67,712 B/img
  const size_t perImgB = szA1 + szA2;              // 315,520 B/img

  int CH = 50;
  const int cands[5] = {400, 200, 100, 67, 50};
  for (int k = 0; k < 5; ++k) {
    if (fixedB + (size_t)cands[k] * perImgB <= ws_size) { CH = cands[k]; break; }
  }
  __hip_bfloat16* A1 = (__hip_bfloat16*)chunk0;
  __hip_bfloat16* A2 = (__hip_bfloat16*)(chunk0 + (size_t)CH * szA1);

  // 1. dtype probe + weight repacks
  fsc_probe_dtype_k<<<1, 256, 0, stream>>>((const unsigned short*)W2, 64 * 64 * 9, flag);
  fsc_repack_w1f_k<<<fsc_cdiv(2048, 256), 256, 0, stream>>>(W1, Wf1, flag);
  fsc_repack_wm_k<<<fsc_cdiv(36864, 256), 256, 0, stream>>>(W2, Wf2, flag);
  fsc_repack_wm_k<<<fsc_cdiv(36864, 256), 256, 0, stream>>>(W3, Wf3, flag);
  fsc_repack_wm_k<<<fsc_cdiv(36864, 256), 256, 0, stream>>>(W4, Wf4, flag);

  // 2. zero NHWC borders (interiors rewritten each chunk; borders stay 0)
  fsc_zero_border_k<44><<<fsc_cdiv(CH * (4 * 44 - 4) * 64, 256), 256, 0, stream>>>(A1, CH);
  fsc_zero_border_k<23><<<fsc_cdiv(CH * (4 * 23 - 4) * 64, 256), 256, 0, stream>>>(A2, CH);
  fsc_zero_border_k<13><<<fsc_cdiv(NTOT * (4 * 13 - 4) * 64, 256), 256, 0, stream>>>(C3, NTOT);

  // 3. chunks over GLOBAL image index (support 0..199, target 200..799)
  for (int g0 = 0; g0 < NTOT; g0 += CH) {
    const int n = imin(CH, NTOT - g0);
    // conv1 fused: <=2 source segments per chunk
    if (g0 < NSUP) {
      const int cnt = imin(g0 + n, NSUP) - g0;
      fsc_conv1f_k<<<fsc_cdiv(cnt * 56, 4), 256, 0, stream>>>(
          xs, g0, Wf1, b1, A1, 0, cnt, flag);
    }
    if (g0 + n > NSUP) {
      const int tStart = imax(g0, NSUP);
      const int cnt = g0 + n - tStart;
      fsc_conv1f_k<<<fsc_cdiv(cnt * 56, 4), 256, 0, stream>>>(
          xt, tStart - NSUP, Wf1, b1, A1, tStart - g0, cnt, flag);
    }
    // conv2: 44-pad -> 21x21 into 23-pad; ROFF=1; TPI=7
    fsc_convm64_k<21, 44, 23, 1><<<fsc_cdiv(n * 7, 4), 256, 0, stream>>>(
        A1, Wf2, b2, A2, n, flag);
    // conv3: 23-pad -> 11x11 into 13-pad; ROFF=0; TPI=2
    fsc_convm64_k<11, 23, 13, 0><<<fsc_cdiv(n * 2, 4), 256, 0, stream>>>(
        A2, Wf3, b3, C3 + (size_t)g0 * 13 * 13 * 64, n, flag);
  }

  // 4. conv4 full batch: 13-pad -> fp32 emb [800][2304]
  fsc_conv4_k<<<fsc_cdiv(NTOT * 2, 4), 256, 0, stream>>>(C3, Wf4, b4, emb, NTOT, flag);

  // 5. head
  fsc_proto_k<<<fsc_cdiv(BB * CC * DD, 256), 256, 0, stream>>>(emb, y, protos);
  fsc_pnorm_k<<<BB * CC, 256, 0, stream>>>(protos, pn);
  fsc_preds_k<<<NTGT, 256, 0, stream>>>(emb + (size_t)NSUP * DD, pn, d_out, flag);
}

// Round 10
// 455.665 us; speedup vs baseline: 1.0451x; 1.0451x over previous
//
#include <hip/hip_runtime.h>
#include <hip/hip_bf16.h>

// Few-shot matching-network head + Conv4 backbone (MI355X, gfx950). Round 10.
//
// R9: 476 us; conv1f (fused register-gather im2col) = 63us x3, MfmaUtil 1.7%,
// VALU 28% -> bound on 16 scattered 4B loads/lane. Fix: structured conv1 loads.
//  - fsc_xform1_k: x -> bf16 NHWC4 [img][86][86][4], c=3 and 2-px right/bottom
//    border zero. Coalesced elementwise transform (~10 us).
//  - fsc_conv1m_k: conv1 as convm64: K laid out (kh, kwp0..3, ci0..3); each
//    quad's 8 k-values = ONE aligned 16B load; kwp=3/ci=3 killed by ZERO
//    WEIGHTS; 2 k-steps, 32 MFMA : 16 loads per wave.
// conv2/3 convm64, conv4, head proven r8/r9 (absmax 0.0039).

#define BB 8
#define SS 25
#define TT 75
#define CC 5
#define DD 2304
#define NSUP 200
#define NTGT 600
#define NTOT 800
#define EPSF 1e-8f

typedef __attribute__((ext_vector_type(8))) short bf16x8;
typedef __attribute__((ext_vector_type(4))) float f32x4;

__device__ __forceinline__ float load_ext(const void* p, size_t idx, int isf32) {
  if (isf32) return ((const float*)p)[idx];
  unsigned short u = ((const unsigned short*)p)[idx];
  union { unsigned int i; float f; } v;
  v.i = ((unsigned int)u) << 16;
  return v.f;
}

// ---- dtype probe (proven r3-r9): flag=1 => external data is fp32 ----
__global__ void fsc_probe_dtype_k(const unsigned short* __restrict__ w2raw,
                                  int nelems, int* __restrict__ flag) {
  __shared__ int cnt;
  if (threadIdx.x == 0) cnt = 0;
  __syncthreads();
  int local = 0;
  for (int i = threadIdx.x; i < nelems; i += 256) {
    unsigned short u = w2raw[i];
    int ex = (u >> 7) & 0xFF;
    if (ex != 0 && (ex < 0x69 || ex > 0x84)) local++;
  }
  atomicAdd(&cnt, local);
  __syncthreads();
  if (threadIdx.x == 0) *flag = (cnt > nelems / 8) ? 1 : 0;
}

// ---- conv1 NHWC4 weight repack: [s=2][t=4][lane=64][j=8] bf16.
//      kk = quad*8+j. s=0: kh=kk>>4, kwp=(kk&15)>>2, ci=kk&3.
//      s=1: kk<16 -> kh=2, kwp=kk>>2, ci=kk&3; kk>=16 -> 0.
//      kwp>=3 or ci>=3 -> 0 (kills the NHWC4 padding lanes). ----
__global__ void fsc_repack_w1m_k(const void* __restrict__ W,
                                 __hip_bfloat16* __restrict__ Wf,
                                 const int* __restrict__ flag) {
  const int isf32 = *flag;
  int i = blockIdx.x * blockDim.x + threadIdx.x;
  if (i >= 4096) return;
  int j = i & 7;
  int lane = (i >> 3) & 63;
  int t = (i >> 9) & 3;
  int s = i >> 11;
  int kk = (lane >> 4) * 8 + j;
  int co = t * 16 + (lane & 15);
  float v = 0.f;
  int kh, kwp, ci;
  bool live = false;
  if (s == 0) { kh = kk >> 4; kwp = (kk & 15) >> 2; ci = kk & 3; live = true; }
  else if (kk < 16) { kh = 2; kwp = kk >> 2; ci = kk & 3; live = true; }
  if (live && kwp < 3 && ci < 3)
    v = load_ext(W, (size_t)((co * 3 + ci) * 3 + kh) * 3 + kwp, isf32);
  Wf[i] = __float2bfloat16(v);
}

// ---- conv2/3/4 weight repack: OIHW [64][64][3][3] -> bf16 A-frag order ----
__global__ void fsc_repack_wm_k(const void* __restrict__ W,
                                __hip_bfloat16* __restrict__ Wf,
                                const int* __restrict__ flag) {
  const int isf32 = *flag;
  int o = blockIdx.x * blockDim.x + threadIdx.x;
  if (o >= 36864) return;
  int j = o & 7;
  int lane = (o >> 3) & 63;
  int t = (o >> 9) & 3;
  int kk = o >> 11;       // 0..17
  int s = kk & 1;
  int khw = kk >> 1;      // kh*3+kw
  int kh = khw / 3, kw = khw - kh * 3;
  int co = t * 16 + (lane & 15);
  int ci = s * 32 + (lane >> 4) * 8 + j;
  float v = load_ext(W, (size_t)((co * 64 + ci) * 3 + kh) * 3 + kw, isf32);
  Wf[o] = __float2bfloat16(v);
}

// ---- zero the 1-px border of an NHWC-padded [N][P][P][64] bf16 buffer ----
template <int P>
__global__ void fsc_zero_border_k(__hip_bfloat16* __restrict__ buf, int N) {
  int i = blockIdx.x * blockDim.x + threadIdx.x;
  const int RP = 4 * P - 4;
  if (i >= N * RP * 64) return;
  int c = i & 63;
  int r = (i >> 6) % RP;
  int n = (i >> 6) / RP;
  int row, colp;
  if (r < P) { row = 0; colp = r; }
  else if (r < 2 * P) { row = P - 1; colp = r - P; }
  else if (r < 3 * P - 2) { row = r - 2 * P + 1; colp = 0; }
  else { row = r - (3 * P - 2) + 1; colp = P - 1; }
  buf[(((size_t)n * P + row) * P + colp) * 64 + c] = __float2bfloat16(0.f);
}

// ---- zero X's pad cells: rows 84..85 (all w) + cols 84..85 (h<84), 4 ch ----
__global__ void fsc_zero_xb_k(__hip_bfloat16* __restrict__ X, int N) {
  int i = blockIdx.x * blockDim.x + threadIdx.x;
  if (i >= N * 1360) return;  // (2*86 + 84*2) * 4
  int c = i & 3;
  int p = (i >> 2) % 340;
  int n = (i >> 2) / 340;
  int h, w;
  if (p < 172) { h = 84 + (p / 86); w = p % 86; }
  else { int pp = p - 172; h = pp >> 1; w = 84 + (pp & 1); }
  X[(((size_t)n * 86 + h) * 86 + w) * 4 + c] = __float2bfloat16(0.f);
}

// ---- input transform: ext [img][3][84][84] -> bf16 NHWC4 [img][86][86][4] ----
__global__ void fsc_xform1_k(const void* __restrict__ x, int srcImg0,
                             __hip_bfloat16* __restrict__ X, int dstImg0,
                             int n, const int* __restrict__ flag) {
  const int isf32 = *flag;
  int i = blockIdx.x * blockDim.x + threadIdx.x;
  const int imgL = i / 7056;
  if (imgL >= n) return;
  const int sp = i - imgL * 7056;
  const int h = sp / 84, w = sp - h * 84;
  const size_t base = (size_t)(srcImg0 + imgL) * 21168;
  union { unsigned short u[4]; uint2 q; } pk;
#pragma unroll
  for (int ci = 0; ci < 3; ++ci)
    pk.u[ci] = __bfloat16_as_ushort(__float2bfloat16(load_ext(x, base + ci * 7056 + sp, isf32)));
  pk.u[3] = 0;
  *(uint2*)(void*)(X + (((size_t)(dstImg0 + imgL) * 86 + h) * 86 + w) * 4) = pk.q;
}

// ---- conv1 MFMA (NHWC4 input): 64 cols/wave, 2 k-steps, out NHWC 44-pad ----
__global__ void fsc_conv1m_k(const __hip_bfloat16* __restrict__ X,
                             const __hip_bfloat16* __restrict__ Wf,
                             const void* __restrict__ bias,
                             __hip_bfloat16* __restrict__ out, int N,
                             const int* __restrict__ flag) {
  constexpr int TPI = 28;  // ceil(1764/64)
  const int wid = blockIdx.x * 4 + (threadIdx.x >> 6);
  const int img = wid / TPI;
  if (img >= N) return;
  const int tl = wid - img * TPI;
  const int lane = threadIdx.x & 63;
  const int nidx = lane & 15, quad = lane >> 4;

  int col[4];
  bool val[4];
  int hoA[4], woA[4];
#pragma unroll
  for (int p = 0; p < 4; ++p) {
    col[p] = tl * 64 + p * 16 + nidx;
    val[p] = col[p] < 1764;
    if (!val[p]) col[p] = 1763;
    hoA[p] = col[p] / 42;
    woA[p] = col[p] - hoA[p] * 42;
  }

  f32x4 acc[4][4];
#pragma unroll
  for (int p = 0; p < 4; ++p)
#pragma unroll
    for (int t = 0; t < 4; ++t) acc[p][t] = (f32x4){0.f, 0.f, 0.f, 0.f};

#pragma unroll
  for (int s = 0; s < 2; ++s) {
    bf16x8 b[4];
#pragma unroll
    for (int p = 0; p < 4; ++p) {
      const int hi = 2 * hoA[p] + (s == 0 ? (quad >> 1) : 2);
      const __hip_bfloat16* bp =
          X + (((size_t)img * 86 + hi) * 86 + 2 * woA[p]) * 4 + (quad & 1) * 8;
      b[p] = *(const bf16x8*)(const void*)bp;
    }
#pragma unroll
    for (int t = 0; t < 4; ++t) {
      bf16x8 a = *(const bf16x8*)(const void*)(Wf + ((size_t)(s * 4 + t) * 64 + lane) * 8);
#pragma unroll
      for (int p = 0; p < 4; ++p)
        acc[p][t] = __builtin_amdgcn_mfma_f32_16x16x32_bf16(a, b[p], acc[p][t], 0, 0, 0);
    }
  }

  const int isf32 = *flag;
#pragma unroll
  for (int p = 0; p < 4; ++p) {
#pragma unroll
    for (int t = 0; t < 4; ++t) {
      float v[4];
#pragma unroll
      for (int r = 0; r < 4; ++r) {
        const int cout = t * 16 + quad * 4 + r;
        float xv = acc[p][t][r] + load_ext(bias, cout, isf32);
        v[r] = xv > 0.f ? xv : 0.f;
      }
      if (val[p]) {
        __hip_bfloat16* o = out + (((size_t)img * 44 + (hoA[p] + 1)) * 44 +
                                   (woA[p] + 1)) * 64 + t * 16 + quad * 4;
        union { unsigned short u[4]; uint2 w; } pk;
#pragma unroll
        for (int r = 0; r < 4; ++r) pk.u[r] = __bfloat16_as_ushort(__float2bfloat16(v[r]));
        *(uint2*)(void*)o = pk.w;
      }
    }
  }
}

// ---- 64-col implicit-GEMM MFMA conv (conv2/conv3; proven r9) ----
template <int HO, int PWI, int PWO, int ROFF>
__global__ void fsc_convm64_k(const __hip_bfloat16* __restrict__ in,
                              const __hip_bfloat16* __restrict__ Wf,
                              const void* __restrict__ bias,
                              __hip_bfloat16* __restrict__ out, int N,
                              const int* __restrict__ flag) {
  constexpr int TPI = (HO * HO + 63) / 64;
  const int wid = blockIdx.x * 4 + (threadIdx.x >> 6);
  const int img = wid / TPI;
  if (img >= N) return;
  const int tl = wid - img * TPI;
  const int lane = threadIdx.x & 63;
  const int nidx = lane & 15, quad = lane >> 4;

  int col[4];
  bool val[4];
  int hoA[4], woA[4];
  const __hip_bfloat16* bsrc[4];
#pragma unroll
  for (int p = 0; p < 4; ++p) {
    col[p] = tl * 64 + p * 16 + nidx;
    val[p] = col[p] < HO * HO;
    if (!val[p]) col[p] = HO * HO - 1;
    hoA[p] = col[p] / HO;
    woA[p] = col[p] - hoA[p] * HO;
    bsrc[p] = in + (((size_t)img * PWI + (2 * hoA[p] + ROFF)) * PWI +
                    (2 * woA[p] + ROFF)) * 64 + quad * 8;
  }
  const __hip_bfloat16* asrc = Wf + lane * 8;

  f32x4 acc[4][4];
#pragma unroll
  for (int p = 0; p < 4; ++p)
#pragma unroll
    for (int t = 0; t < 4; ++t) acc[p][t] = (f32x4){0.f, 0.f, 0.f, 0.f};

#pragma unroll
  for (int kk = 0; kk < 18; ++kk) {
    const int s = kk & 1;
    const int khw = kk >> 1;
    const int kh = khw / 3, kw = khw - kh * 3;
    const int boff = (kh * PWI + kw) * 64 + s * 32;
    bf16x8 b[4];
#pragma unroll
    for (int p = 0; p < 4; ++p) b[p] = *(const bf16x8*)(const void*)(bsrc[p] + boff);
#pragma unroll
    for (int t = 0; t < 4; ++t) {
      bf16x8 a = *(const bf16x8*)(const void*)(asrc + (kk * 4 + t) * 512);
#pragma unroll
      for (int p = 0; p < 4; ++p)
        acc[p][t] = __builtin_amdgcn_mfma_f32_16x16x32_bf16(a, b[p], acc[p][t], 0, 0, 0);
    }
  }

  const int isf32 = *flag;
#pragma unroll
  for (int p = 0; p < 4; ++p) {
#pragma unroll
    for (int t = 0; t < 4; ++t) {
      float v[4];
#pragma unroll
      for (int r = 0; r < 4; ++r) {
        const int cout = t * 16 + quad * 4 + r;
        float xv = acc[p][t][r] + load_ext(bias, cout, isf32);
        v[r] = xv > 0.f ? xv : 0.f;
      }
      if (val[p]) {
        __hip_bfloat16* o = out + (((size_t)img * PWO + (hoA[p] + 1)) * PWO +
                                   (woA[p] + 1)) * 64 + t * 16 + quad * 4;
        union { unsigned short u[4]; uint2 w; } pk;
#pragma unroll
        for (int r = 0; r < 4; ++r) pk.u[r] = __bfloat16_as_ushort(__float2bfloat16(v[r]));
        *(uint2*)(void*)o = pk.w;
      }
    }
  }
}

// ---- 32-col MFMA conv, EMB output (conv4; proven r6-r9) ----
__global__ void fsc_conv4_k(const __hip_bfloat16* __restrict__ in,
                            const __hip_bfloat16* __restrict__ Wf,
                            const void* __restrict__ bias, float* __restrict__ emb,
                            int N, const int* __restrict__ flag) {
  constexpr int HO = 6, PWI = 13;
  constexpr int TPI = 2;  // ceil(36/32)
  const int wid = blockIdx.x * 4 + (threadIdx.x >> 6);
  const int img = wid / TPI;
  if (img >= N) return;
  const int tl = wid - img * TPI;
  const int lane = threadIdx.x & 63;
  const int nidx = lane & 15, quad = lane >> 4;

  int col0 = tl * 32 + nidx;
  int col1 = col0 + 16;
  const bool val0 = col0 < HO * HO;
  const bool val1 = col1 < HO * HO;
  if (!val0) col0 = HO * HO - 1;
  if (!val1) col1 = HO * HO - 1;
  const int ho0 = col0 / HO, wo0 = col0 - ho0 * HO;
  const int ho1 = col1 / HO, wo1 = col1 - ho1 * HO;

  const __hip_bfloat16* bsrc0 =
      in + (((size_t)img * PWI + 2 * ho0) * PWI + 2 * wo0) * 64 + quad * 8;
  const __hip_bfloat16* bsrc1 =
      in + (((size_t)img * PWI + 2 * ho1) * PWI + 2 * wo1) * 64 + quad * 8;
  const __hip_bfloat16* asrc = Wf + lane * 8;

  f32x4 acc[2][4];
#pragma unroll
  for (int p = 0; p < 2; ++p)
#pragma unroll
    for (int t = 0; t < 4; ++t) acc[p][t] = (f32x4){0.f, 0.f, 0.f, 0.f};

#pragma unroll
  for (int kk = 0; kk < 18; ++kk) {
    const int s = kk & 1;
    const int khw = kk >> 1;
    const int kh = khw / 3, kw = khw - kh * 3;
    const int boff = (kh * PWI + kw) * 64 + s * 32;
    bf16x8 b0 = *(const bf16x8*)(const void*)(bsrc0 + boff);
    bf16x8 b1 = *(const bf16x8*)(const void*)(bsrc1 + boff);
#pragma unroll
    for (int t = 0; t < 4; ++t) {
      bf16x8 a = *(const bf16x8*)(const void*)(asrc + (kk * 4 + t) * 512);
      acc[0][t] = __builtin_amdgcn_mfma_f32_16x16x32_bf16(a, b0, acc[0][t], 0, 0, 0);
      acc[1][t] = __builtin_amdgcn_mfma_f32_16x16x32_bf16(a, b1, acc[1][t], 0, 0, 0);
    }
  }

  const int isf32 = *flag;
#pragma unroll
  for (int p = 0; p < 2; ++p) {
    const bool valid = p == 0 ? val0 : val1;
    const int col = p == 0 ? col0 : col1;
#pragma unroll
    for (int t = 0; t < 4; ++t) {
      float v[4];
#pragma unroll
      for (int r = 0; r < 4; ++r) {
        const int cout = t * 16 + quad * 4 + r;
        float xv = acc[p][t][r] + load_ext(bias, cout, isf32);
        v[r] = xv > 0.f ? xv : 0.f;
      }
      if (valid) {
        float* o = emb + ((size_t)img * 36 + col) * 64 + t * 16 + quad * 4;
        *(f32x4*)(void*)o = (f32x4){v[0], v[1], v[2], v[3]};
      }
    }
  }
}

// ---- head (proven r3-r9) ----
__global__ void fsc_proto_k(const float* __restrict__ emb_s, const int* __restrict__ y,
                            float* __restrict__ protos) {
  int i = blockIdx.x * blockDim.x + threadIdx.x;
  if (i >= BB * CC * DD) return;
  int d = i % DD;
  int bc = i / DD;
  int c = bc % CC;
  int b = bc / CC;
  float sum = 0.f;
  for (int s = 0; s < SS; ++s) {
    if (y[b * SS + s] % CC == c) sum += emb_s[(size_t)(b * SS + s) * DD + d];
  }
  protos[i] = sum * 0.2f;
}

__global__ void fsc_pnorm_k(const float* __restrict__ protos, float* __restrict__ pn) {
  __shared__ float red[4];
  __shared__ float inv;
  const int bc = blockIdx.x;
  const float* p = protos + (size_t)bc * DD;
  float ss = 0.f;
  for (int d = threadIdx.x; d < DD; d += 256) { float v = p[d]; ss += v * v; }
#pragma unroll
  for (int off = 32; off > 0; off >>= 1) ss += __shfl_down(ss, off);
  if ((threadIdx.x & 63) == 0) red[threadIdx.x >> 6] = ss;
  __syncthreads();
  if (threadIdx.x == 0) {
    float nrm = sqrtf(red[0] + red[1] + red[2] + red[3]);
    nrm = nrm > EPSF ? nrm : EPSF;
    inv = 1.f / nrm;
  }
  __syncthreads();
  float sc = inv;
  for (int d = threadIdx.x; d < DD; d += 256) pn[(size_t)bc * DD + d] = p[d] * sc;
}

__global__ void fsc_preds_k(const float* __restrict__ emb_t, const float* __restrict__ pn,
                            void* __restrict__ out, const int* __restrict__ flag) {
  __shared__ float red[4][6];
  __shared__ float fin[6];
  const int isf32 = *flag;
  const int bt = blockIdx.x;
  const int b = bt / TT;
  const float* et = emb_t + (size_t)bt * DD;
  float e[9];
#pragma unroll
  for (int k = 0; k < 9; ++k) e[k] = et[threadIdx.x + 256 * k];
  float vals[6];
  {
    float ss = 0.f;
#pragma unroll
    for (int k = 0; k < 9; ++k) ss += e[k] * e[k];
    vals[0] = ss;
  }
  const float* pb = pn + (size_t)b * CC * DD;
#pragma unroll
  for (int c = 0; c < CC; ++c) {
    float s = 0.f;
#pragma unroll
    for (int k = 0; k < 9; ++k) s += e[k] * pb[(size_t)c * DD + threadIdx.x + 256 * k];
    vals[1 + c] = s;
  }
#pragma unroll
  for (int v = 0; v < 6; ++v) {
#pragma unroll
    for (int off = 32; off > 0; off >>= 1) vals[v] += __shfl_down(vals[v], off);
  }
  if ((threadIdx.x & 63) == 0) {
#pragma unroll
    for (int v = 0; v < 6; ++v) red[threadIdx.x >> 6][v] = vals[v];
  }
  __syncthreads();
  if (threadIdx.x < 6)
    fin[threadIdx.x] = red[0][threadIdx.x] + red[1][threadIdx.x] +
                       red[2][threadIdx.x] + red[3][threadIdx.x];
  __syncthreads();
  if (threadIdx.x < CC) {
    float nt = sqrtf(fin[0]);
    nt = nt > EPSF ? nt : EPSF;
    float r = fin[1 + threadIdx.x] / nt;
    if (isf32) ((float*)out)[(size_t)bt * CC + threadIdx.x] = r;
    else ((__hip_bfloat16*)out)[(size_t)bt * CC + threadIdx.x] = __float2bfloat16(r);
  }
}

static inline int fsc_cdiv(int a, int b) { return (a + b - 1) / b; }
static inline int imin(int a, int b) { return a < b ? a : b; }
static inline int imax(int a, int b) { return a > b ? a : b; }

extern "C" void kernel_launch(void* const* d_in, const int* in_sizes, int n_in,
                              void* d_out, int out_size, void* d_ws, size_t ws_size,
                              hipStream_t stream) {
  const void* xs = d_in[0];
  const void* xt = d_in[1];
  const int* y = (const int*)d_in[2];
  const void* W1 = d_in[3];
  const void* b1 = d_in[4];
  const void* W2 = d_in[5];
  const void* b2 = d_in[6];
  const void* W3 = d_in[7];
  const void* b3 = d_in[8];
  const void* W4 = d_in[9];
  const void* b4 = d_in[10];

  // ---- workspace layout: fixed ~25.6 MB + X/A1/A2 chunk buffers ----
  char* w = (char*)d_ws;
  int* flag = (int*)w;                      w += 256;
  __hip_bfloat16* Wf1 = (__hip_bfloat16*)w; w += 4096 * 2;
  __hip_bfloat16* Wf2 = (__hip_bfloat16*)w; w += 36864 * 2;
  __hip_bfloat16* Wf3 = (__hip_bfloat16*)w; w += 36864 * 2;
  __hip_bfloat16* Wf4 = (__hip_bfloat16*)w; w += 36864 * 2;
  float* protos = (float*)w;                w += (size_t)BB * CC * DD * 4;
  float* pn = (float*)w;                    w += (size_t)BB * CC * DD * 4;
  float* emb = (float*)w;                   w += (size_t)NTOT * DD * 4;           // 7.37 MB
  __hip_bfloat16* C3 = (__hip_bfloat16*)w;  w += (size_t)NTOT * 13 * 13 * 64 * 2; // 17.3 MB
  char* chunk0 = w;
  const size_t fixedB = (size_t)(w - (char*)d_ws);
  const size_t szX  = (size_t)86 * 86 * 4 * 2;    //  59,168 B/img
  const size_t szA1 = (size_t)44 * 44 * 64 * 2;   // 247,808 B/img
  const size_t szA2 = (size_t)23 * 23 * 64 * 2;   //  67,712 B/img
  const size_t perImgB = szX + szA1 + szA2;        // 374,688 B/img

  int CH = 50;
  const int cands[5] = {400, 200, 100, 67, 50};
  for (int k = 0; k < 5; ++k) {
    if (fixedB + (size_t)cands[k] * perImgB <= ws_size) { CH = cands[k]; break; }
  }
  __hip_bfloat16* X  = (__hip_bfloat16*)chunk0;
  __hip_bfloat16* A1 = (__hip_bfloat16*)(chunk0 + (size_t)CH * szX);
  __hip_bfloat16* A2 = (__hip_bfloat16*)(chunk0 + (size_t)CH * (szX + szA1));

  // 1. dtype probe + weight repacks
  fsc_probe_dtype_k<<<1, 256, 0, stream>>>((const unsigned short*)W2, 64 * 64 * 9, flag);
  fsc_repack_w1m_k<<<fsc_cdiv(4096, 256), 256, 0, stream>>>(W1, Wf1, flag);
  fsc_repack_wm_k<<<fsc_cdiv(36864, 256), 256, 0, stream>>>(W2, Wf2, flag);
  fsc_repack_wm_k<<<fsc_cdiv(36864, 256), 256, 0, stream>>>(W3, Wf3, flag);
  fsc_repack_wm_k<<<fsc_cdiv(36864, 256), 256, 0, stream>>>(W4, Wf4, flag);

  // 2. zero pad cells (interiors rewritten each chunk; pads stay 0)
  fsc_zero_xb_k<<<fsc_cdiv(CH * 1360, 256), 256, 0, stream>>>(X, CH);
  fsc_zero_border_k<44><<<fsc_cdiv(CH * (4 * 44 - 4) * 64, 256), 256, 0, stream>>>(A1, CH);
  fsc_zero_border_k<23><<<fsc_cdiv(CH * (4 * 23 - 4) * 64, 256), 256, 0, stream>>>(A2, CH);
  fsc_zero_border_k<13><<<fsc_cdiv(NTOT * (4 * 13 - 4) * 64, 256), 256, 0, stream>>>(C3, NTOT);

  // 3. chunks over GLOBAL image index (support 0..199, target 200..799)
  for (int g0 = 0; g0 < NTOT; g0 += CH) {
    const int n = imin(CH, NTOT - g0);
    // xform: <=2 source segments per chunk
    if (g0 < NSUP) {
      const int cnt = imin(g0 + n, NSUP) - g0;
      fsc_xform1_k<<<fsc_cdiv(cnt * 7056, 256), 256, 0, stream>>>(
          xs, g0, X, 0, cnt, flag);
    }
    if (g0 + n > NSUP) {
      const int tStart = imax(g0, NSUP);
      const int cnt = g0 + n - tStart;
      fsc_xform1_k<<<fsc_cdiv(cnt * 7056, 256), 256, 0, stream>>>(
          xt, tStart - NSUP, X, tStart - g0, cnt, flag);
    }
    // conv1: NHWC4 -> 42x42 into 44-pad; TPI=28
    fsc_conv1m_k<<<fsc_cdiv(n * 28, 4), 256, 0, stream>>>(X, Wf1, b1, A1, n, flag);
    // conv2: 44-pad -> 21x21 into 23-pad; ROFF=1; TPI=7
    fsc_convm64_k<21, 44, 23, 1><<<fsc_cdiv(n * 7, 4), 256, 0, stream>>>(
        A1, Wf2, b2, A2, n, flag);
    // conv3: 23-pad -> 11x11 into 13-pad; ROFF=0; TPI=2
    fsc_convm64_k<11, 23, 13, 0><<<fsc_cdiv(n * 2, 4), 256, 0, stream>>>(
        A2, Wf3, b3, C3 + (size_t)g0 * 13 * 13 * 64, n, flag);
  }

  // 4. conv4 full batch: 13-pad -> fp32 emb [800][2304]
  fsc_conv4_k<<<fsc_cdiv(NTOT * 2, 4), 256, 0, stream>>>(C3, Wf4, b4, emb, NTOT, flag);

  // 5. head
  fsc_proto_k<<<fsc_cdiv(BB * CC * DD, 256), 256, 0, stream>>>(emb, y, protos);
  fsc_pnorm_k<<<BB * CC, 256, 0, stream>>>(protos, pn);
  fsc_preds_k<<<NTGT, 256, 0, stream>>>(emb + (size_t)NSUP * DD, pn, d_out, flag);
}